// Round 14
// baseline (346.154 us; speedup 1.0000x reference)
//
#include <hip/hip_runtime.h>
#include <math.h>

// ---------------------------------------------------------------------------
// Problem dims: B_IN=15, B1=10, B2=6, F1=20, F2=40, F_OUT=10
// M1=19, C1=9, M2=11, C2=5, batch=128
// VALID(l,m,n): |m-5|<=l && |n-5|<=l -> 286 of 726; packed base(l)=l(4l^2-1)/3
// HALF set (z2 Hermitian): dm>0 or (dm==0 && dn>=0) -> 146, l-DESCENDING.
// Parity identities (exact):
//   E_A1[mi, a+10] = (-1)^(mi-9) E_A1[mi, a]
//   E_A1[n,  g+10] = (-1)^(n-9)  E_A1[n,  g]   (g-pair fold)
//   FF2[5+d, a+10] = (-1)^d FF2[5+d, a]
//   FF2[ni,  g+10] = (-1)^(ni-5) FF2[ni, g]    (ymn g-fold)
//   E_A2[5+d, a+6] = (-1)^d E_A2[5+d, a]
//   ymn[10-mi,10-ni] = conj(ymn[mi,ni])        (y real)
// ---------------------------------------------------------------------------

constexpr int OFF_WS2   = 0;                      // W_S2_FWD  [30][10][19]
constexpr int OFF_WINV1 = OFF_WS2   + 5700;       // W_INV1    [20][10][19][19] (m>=9 rows only built)
constexpr int OFF_WSO3  = OFF_WINV1 + 72200;      // W_SO3_FWD [20][6][11][11]
constexpr int OFF_WINV2 = OFF_WSO3  + 14520;      // W_INV2    [12][6][11][11] (m>=5 rows only built)
constexpr int OFF_WINT  = OFF_WINV2 + 8712;       // W_INT     [12] (+pad)
constexpr int OFF_FE1   = OFF_WINT  + 16;         // FE1  cplx [19][30]
constexpr int OFF_EA1   = OFF_FE1   + 1140;       // E_A1 cplx [19][20]
constexpr int OFF_FF2   = OFF_EA1   + 760;        // FF2  cplx [11][20]
constexpr int OFF_EA2   = OFF_FF2   + 440;        // E_A2 cplx [11][12]
constexpr int OFF_BS2   = OFF_EA2   + 264;        // B_S2 cplx [24][10][19]
constexpr int OFF_BSO3  = OFF_BS2   + 9120;       // B_SO3 cplx[144][6][11][11] (half-set only built)
constexpr int OFF_PSI   = OFF_BSO3  + 209088;     // psi  cplx [20][10][19]
constexpr int OFF_X     = OFF_PSI   + 7600;       // X    cplx [128][10][19]
constexpr int OFF_X2P   = OFF_X     + 48640;      // X2 packed [128][20][286] cplx
constexpr int OFF_PSI2P = OFF_X2P   + 1464320;    // psi2 packed [20][40][286] cplx
constexpr int OFF_FEAT  = OFF_PSI2P + 457600;     // feat      [128][40]
constexpr int OFF_VTAB  = OFF_FEAT  + 5120;       // int[286] valid (l,m,n)
constexpr int OFF_VTAB2 = OFF_VTAB  + 286;        // int[146] half-set, l desc

#define DPI 3.14159265358979323846

// ---------------------------------------------------------------------------
__device__ __forceinline__ double dfact(int n) {
    double f = 1.0;
    for (int i = 2; i <= n; ++i) f *= (double)i;
    return f;
}
__device__ __forceinline__ double dpowi(double x, int n) {
    double r = 1.0;
    for (int i = 0; i < n; ++i) r *= x;
    return r;
}
__device__ double wig_d(int l, int mi, int ni, double beta) {
    int m = mi - l, n = ni - l;
    double cb = cos(0.5 * beta), sb = sin(0.5 * beta);
    double pref = sqrt(dfact(l + m) * dfact(l - m) * dfact(l + n) * dfact(l - n));
    int s0 = (n - m) > 0 ? (n - m) : 0;
    int s1 = (l + n) < (l - m) ? (l + n) : (l - m);
    double v = 0.0;
    for (int s = s0; s <= s1; ++s) {
        double term = dpowi(cb, 2 * l + n - m - 2 * s) * dpowi(sb, m - n + 2 * s) /
                      (dfact(l + n - s) * dfact(s) * dfact(m - n + s) * dfact(l - m - s));
        v += ((m - n + s) & 1) ? -term : term;
    }
    return pref * v;
}
__device__ double wig_pad(int l, int m, int n, int c, double beta) {
    if (m < c - l || m > c + l || n < c - l || n > c + l) return 0.0;
    return wig_d(l, m - (c - l), n - (c - l), beta);
}
__device__ double quad_w(int b, int k) {
    double beta = DPI * (2 * k + 1) / (4.0 * b);
    double s = 0.0;
    for (int j = 0; j < b; ++j) s += sin((2 * j + 1) * beta) / (double)(2 * j + 1);
    return 2.0 / b * sin(beta) * s;
}

// element ids total = 211982 (unread entries skipped)
__global__ __launch_bounds__(256) void build_tables_kernel(float* ws) {
    int idx = blockIdx.x * 256 + threadIdx.x;
    if (idx < 5700) {
        int k = idx / 190, r = idx % 190, l = r / 19, m = r % 19;
        double beta = DPI * (2 * k + 1) / 60.0;
        ws[OFF_WS2 + idx] = (float)(quad_w(15, k) * wig_pad(l, m, 9, 9, beta));
        return;
    }
    idx -= 5700;
    if (idx < 72200) {
        int k = idx / 3610, r = idx % 3610, l = r / 361, r2 = r % 361, m = r2 / 19, n = r2 % 19;
        if (m < 9) return;   // stage1 reads only mi>=9 rows
        double beta = DPI * (2 * k + 1) / 40.0;
        ws[OFF_WINV1 + idx] = (float)((2 * l + 1) * wig_pad(l, m, n, 9, beta));
        return;
    }
    idx -= 72200;
    if (idx < 14520) {
        int k = idx / 726, r = idx % 726, l = r / 121, m = (r % 121) / 11, n = r % 11;
        double beta = DPI * (2 * k + 1) / 40.0;
        ws[OFF_WSO3 + idx] = (float)(quad_w(10, k) * wig_pad(l, m, n, 5, beta));
        return;
    }
    idx -= 14520;
    if (idx < 8712) {
        int k = idx / 726, r = idx % 726, l = r / 121, m = (r % 121) / 11, n = r % 11;
        if (m < 5) return;   // stage2 phase C reads only m>=5 rows
        double beta = DPI * (2 * k + 1) / 24.0;
        ws[OFF_WINV2 + idx] = (float)((2 * l + 1) * wig_pad(l, m, n, 5, beta));
        return;
    }
    idx -= 8712;
    if (idx < 12) { ws[OFF_WINT + idx] = (float)quad_w(6, idx); return; }
    idx -= 12;
    if (idx < 570) {
        int m = idx / 30, t = idx % 30;
        double ang = -2.0 * DPI * (double)((m - 9) * t) / 30.0;
        ws[OFF_FE1 + 2 * idx] = (float)cos(ang);
        ws[OFF_FE1 + 2 * idx + 1] = (float)sin(ang);
        return;
    }
    idx -= 570;
    if (idx < 380) {
        int m = idx / 20, a = idx % 20;
        double ang = 2.0 * DPI * (double)((m - 9) * a) / 20.0;
        ws[OFF_EA1 + 2 * idx] = (float)cos(ang);
        ws[OFF_EA1 + 2 * idx + 1] = (float)sin(ang);
        return;
    }
    idx -= 380;
    if (idx < 220) {
        int m = idx / 20, a = idx % 20;
        double ang = -2.0 * DPI * (double)((m - 5) * a) / 20.0;
        ws[OFF_FF2 + 2 * idx] = (float)cos(ang);
        ws[OFF_FF2 + 2 * idx + 1] = (float)sin(ang);
        return;
    }
    idx -= 220;
    if (idx < 132) {
        int m = idx / 12, a = idx % 12;
        double ang = 2.0 * DPI * (double)((m - 5) * a) / 12.0;
        ws[OFF_EA2 + 2 * idx] = (float)cos(ang);
        ws[OFF_EA2 + 2 * idx + 1] = (float)sin(ang);
        return;
    }
    idx -= 132;
    if (idx < 4560) {
        int p = idx / 190, r = idx % 190, l = r / 19, m = r % 19;
        int bi = p / 8, ai = p % 8;
        double beta = (bi + 1) * (DPI / 24.0);
        double alpha = 2.0 * DPI * ai / 8.0;
        double re = 0.0, im = 0.0;
        if (m - 9 >= -l && m - 9 <= l) {
            double d = wig_d(l, m - 9 + l, l, beta);
            double ang = -(double)(m - 9) * alpha;
            re = d * cos(ang); im = d * sin(ang);
        }
        ws[OFF_BS2 + 2 * idx] = (float)re;
        ws[OFF_BS2 + 2 * idx + 1] = (float)im;
        return;
    }
    idx -= 4560;
    if (idx < 104544) {
        int p = idx / 726, r = idx % 726, l = r / 121, m = (r % 121) / 11, n = r % 11;
        int dm = m - 5, dn = n - 5;
        int am = dm < 0 ? -dm : dm, an = dn < 0 ? -dn : dn;
        if (am > l || an > l) return;                       // structurally zero
        if (!((dm > 0) || (dm == 0 && dn >= 0))) return;    // psi2 reads half-set only
        int bi = p / 48, ai = (p % 48) / 6, gi = p % 6;
        double beta = (bi + 1) * (DPI / 24.0);
        double alpha = 2.0 * DPI * ai / 8.0;
        double gamma = 2.0 * DPI * gi / 6.0;
        double d = wig_d(l, m - 5 + l, n - 5 + l, beta);
        double ang = -((double)(m - 5) * alpha + (double)(n - 5) * gamma);
        ws[OFF_BSO3 + 2 * idx] = (float)(d * cos(ang));
        ws[OFF_BSO3 + 2 * idx + 1] = (float)(d * sin(ang));
        return;
    }
    idx -= 104544;
    if (idx < 286) {
        int l = 0, cum = 0;
        while (idx >= cum + (2 * l + 1) * (2 * l + 1)) { cum += (2 * l + 1) * (2 * l + 1); ++l; }
        int rem = idx - cum, w = 2 * l + 1;
        int m = 5 - l + rem / w, n = 5 - l + rem % w;
        ((int*)(ws + OFF_VTAB))[idx] = l | (m << 4) | (n << 8);
        return;
    }
    idx -= 286;
    if (idx < 146) {
        int l = 5, st = 0;
        while (idx >= st + (2 * l * l + 2 * l + 1)) { st += 2 * l * l + 2 * l + 1; --l; }
        int rem = idx - st;
        int dm, dn;
        if (rem < l + 1) { dm = 0; dn = rem; }
        else { int r2 = rem - (l + 1); dm = 1 + r2 / (2 * l + 1); dn = r2 % (2 * l + 1) - l; }
        ((int*)(ws + OFF_VTAB2))[idx] = l | ((dm + 5) << 4) | ((dn + 5) << 8);
        return;
    }
}

// ---------------------------------------------------------------------------
// prep_kernel: psi2 (blocks 0..456) + xform1 (457..584) + psi1 (585..599)
// ---------------------------------------------------------------------------
__global__ __launch_bounds__(256) void prep_kernel(float* ws,
                                                   const float* __restrict__ k1,
                                                   const float* __restrict__ k2,
                                                   const float* __restrict__ x) {
    const int bid = blockIdx.x, tid = threadIdx.x;
    __shared__ float xs[900];
    __shared__ float2 xm[570];

    if (bid < 457) {
        int idx = bid * 256 + tid;
        if (idx >= 116800) return;
        int i = idx / 5840, r = idx % 5840, o = r / 146, h = r % 146;
        int w = ((const int*)(ws + OFF_VTAB2))[h];
        int l = w & 15, dm = ((w >> 4) & 15) - 5, dn = ((w >> 8) & 15) - 5;
        int lmn = l * 121 + (dm + 5) * 11 + (dn + 5);
        const float2* BS = (const float2*)(ws + OFF_BSO3);
        float2 s = {0.f, 0.f};
        for (int p = 0; p < 144; ++p) {
            float wv = k2[(i * 40 + o) * 144 + p];
            float2 bv = BS[p * 726 + lmn];
            s.x += wv * bv.x; s.y += wv * bv.y;
        }
        float2* row = (float2*)(ws + OFF_PSI2P) + (i * 40 + o) * 286;
        int base = l * (4 * l * l - 1) / 3, span = 2 * l + 1;
        row[base + (dm + l) * span + (dn + l)] = s;
        float sign = ((dm + dn + 16) & 1) ? -1.f : 1.f;
        row[base + (-dm + l) * span + (-dn + l)] = make_float2(sign * s.x, -sign * s.y);
        return;
    }
    if (bid < 585) {
        const int b = bid - 457;
        const float2* FE1 = (const float2*)(ws + OFF_FE1);
        const float* WS2 = ws + OFF_WS2;
        float2* Xg = (float2*)(ws + OFF_X) + b * 190;
        for (int i = tid; i < 900; i += 256) xs[i] = x[b * 900 + i];
        __syncthreads();
        for (int i = tid; i < 570; i += 256) {
            int k = i / 19, m = i % 19;
            float2 s = {0.f, 0.f};
            #pragma unroll
            for (int t = 0; t < 30; ++t) {
                float v = xs[k * 30 + t];
                float2 e = FE1[m * 30 + t];
                s.x += v * e.x; s.y += v * e.y;
            }
            xm[k * 19 + m] = s;
        }
        __syncthreads();
        for (int i = tid; i < 190; i += 256) {
            int l = i / 19, m = i % 19;
            float2 s = {0.f, 0.f};
            for (int k = 0; k < 30; ++k) {
                float w = WS2[k * 190 + l * 19 + m];
                float2 v = xm[k * 19 + m];
                s.x += w * v.x; s.y += w * v.y;
            }
            Xg[i] = s;
        }
        return;
    }
    {
        int idx = (bid - 585) * 256 + tid;
        if (idx >= 3800) return;
        int o = idx / 190, r = idx % 190;
        const float2* BS2 = (const float2*)(ws + OFF_BS2);
        float2 s = {0.f, 0.f};
        for (int p = 0; p < 24; ++p) {
            float w = k1[o * 24 + p];
            float2 bv = BS2[p * 190 + r];
            s.x += w * bv.x; s.y += w * bv.y;
        }
        ((float2*)(ws + OFF_PSI))[idx] = s;
    }
}

// ---------------------------------------------------------------------------
// stage1 v10 (unchanged, r13-validated)
// ---------------------------------------------------------------------------
__global__ __launch_bounds__(256, 3) void stage1_kernel(
    const float* __restrict__ WI1, const float* __restrict__ WS3,
    const float* __restrict__ EA1, const float* __restrict__ FF2,
    const float2* __restrict__ Xall, const float2* __restrict__ Pall,
    const int* __restrict__ VTAB, float2* __restrict__ X2out)
{
    const int tid = threadIdx.x;
    const int b = blockIdx.x / 20;
    const int o = blockIdx.x % 20;
    const float2* Xg = Xall + b * 190;
    const float2* Pg = Pall + o * 190;
    float2* X2g = X2out + (b * 20 + o) * 286;
    const float2* EA1c = (const float2*)EA1;
    const float2* FF2c = (const float2*)FF2;

    __shared__ float2 Xs[190], Ps[190], FF2s[220];
    __shared__ float2 fhA[3800];
    __shared__ float2 ymnA[1320];

    const int gpair = tid % 10;
    const int kk = tid / 10;
    const bool active = (tid < 200);

    float2 eg[19];
    #pragma unroll
    for (int n = 0; n < 19; ++n) eg[n] = EA1c[n * 20 + gpair];

    for (int i = tid; i < 190; i += 256) { Xs[i] = Xg[i]; Ps[i] = Pg[i]; }
    for (int i = tid; i < 220; i += 256) FF2s[i] = FF2c[i];
    __syncthreads();

    // (a) fh build block-wide
    for (int i = tid; i < 3800; i += 256) {
        int k = i / 190, idx = i - k * 190;
        int mrow = idx / 19, ni = idx - mrow * 19;
        int mi = mrow + 9;
        int an = ni > 9 ? ni - 9 : 9 - ni;
        int lmin = mrow > an ? mrow : an;
        const float* wk = WI1 + k * 3610 + mi * 19 + ni;
        float2 s = {0.f, 0.f};
        for (int l = lmin; l < 10; ++l) {
            float2 a = Xs[l * 19 + mi], c = Ps[l * 19 + ni];
            float wv = wk[l * 361];
            s.x += wv * (a.x * c.x + a.y * c.y);
            s.y += wv * (a.y * c.x - a.x * c.y);
        }
        fhA[i] = s;
    }
    __syncthreads();

    // (b) per-lane column-PAIR pipeline
    float2 uacc0[6], uacc1[6];
    if (active) {
        const float2* fhk = fhA + kk * 190;
        float ye0[10], yo0[10], ye1[10], yo1[10];
        {
            float2 te = {0.f, 0.f}, to = {0.f, 0.f};
            #pragma unroll
            for (int n = 0; n < 19; ++n) {
                float2 f = fhk[n];
                float rx = f.x * eg[n].x - f.y * eg[n].y;
                float ry = f.x * eg[n].y + f.y * eg[n].x;
                if (n & 1) { te.x += rx; te.y += ry; }
                else       { to.x += rx; to.y += ry; }
            }
            float t0x = te.x + to.x, t1x = te.x - to.x;
            #pragma unroll
            for (int a = 0; a < 10; ++a) {
                ye0[a] = t0x; yo0[a] = 0.f;
                ye1[a] = t1x; yo1[a] = 0.f;
            }
        }
        #pragma unroll 1   // r7 lesson: full unroll -> VGPR cliff
        for (int mrow = 1; mrow < 10; ++mrow) {
            float2 te = {0.f, 0.f}, to = {0.f, 0.f};
            #pragma unroll
            for (int n = 0; n < 19; ++n) {
                float2 f = fhk[mrow * 19 + n];
                float rx = f.x * eg[n].x - f.y * eg[n].y;
                float ry = f.x * eg[n].y + f.y * eg[n].x;
                if (n & 1) { te.x += rx; te.y += ry; }
                else       { to.x += rx; to.y += ry; }
            }
            float2 t0 = make_float2(2.f * (te.x + to.x), 2.f * (te.y + to.y));
            float2 t1 = make_float2(2.f * (te.x - to.x), 2.f * (te.y - to.y));
            if (mrow & 1) {
                #pragma unroll
                for (int a = 0; a < 10; ++a) {
                    float2 e = EA1c[(9 + mrow) * 20 + a];
                    yo0[a] += t0.x * e.x - t0.y * e.y;
                    yo1[a] += t1.x * e.x - t1.y * e.y;
                }
            } else {
                #pragma unroll
                for (int a = 0; a < 10; ++a) {
                    float2 e = EA1c[(9 + mrow) * 20 + a];
                    ye0[a] += t0.x * e.x - t0.y * e.y;
                    ye1[a] += t1.x * e.x - t1.y * e.y;
                }
            }
        }
        #pragma unroll
        for (int a = 0; a < 10; ++a) {
            float p0 = ye0[a] + yo0[a]; p0 = p0 > 0.f ? p0 : 0.f;
            float q0 = ye0[a] - yo0[a]; q0 = q0 > 0.f ? q0 : 0.f;
            ye0[a] = p0 + q0; yo0[a] = p0 - q0;
            float p1 = ye1[a] + yo1[a]; p1 = p1 > 0.f ? p1 : 0.f;
            float q1 = ye1[a] - yo1[a]; q1 = q1 > 0.f ? q1 : 0.f;
            ye1[a] = p1 + q1; yo1[a] = p1 - q1;
        }
        uacc0[0] = make_float2(0.f, 0.f); uacc1[0] = make_float2(0.f, 0.f);
        #pragma unroll
        for (int a = 0; a < 10; ++a) { uacc0[0].x += ye0[a]; uacc1[0].x += ye1[a]; }
        #pragma unroll
        for (int d = 1; d < 6; ++d) {
            uacc0[d] = make_float2(0.f, 0.f); uacc1[d] = make_float2(0.f, 0.f);
            #pragma unroll
            for (int a = 0; a < 10; ++a) {
                float q0 = (d & 1) ? yo0[a] : ye0[a];
                float q1 = (d & 1) ? yo1[a] : ye1[a];
                float2 e = FF2c[(5 + d) * 20 + a];
                uacc0[d].x += e.x * q0; uacc0[d].y += e.y * q0;
                uacc1[d].x += e.x * q1; uacc1[d].y += e.y * q1;
            }
        }
    }
    __syncthreads();

    // (c) uu compact write [k][6][20], aliases fhA
    float2* uubuf = fhA;
    if (active) {
        #pragma unroll
        for (int d = 0; d < 6; ++d) {
            uubuf[kk * 120 + d * 20 + gpair]      = uacc0[d];
            uubuf[kk * 120 + d * 20 + gpair + 10] = uacc1[d];
        }
    }
    __syncthreads();

    // (d) ymn rows mi=5..10, g-FOLDED
    for (int i = tid; i < 1320; i += 256) {
        int k = i / 66, rr = i - k * 66;
        int d = rr / 11, ni = rr - d * 11;
        const float2* uurow = uubuf + k * 120 + d * 20;
        float sgn = (ni & 1) ? 1.f : -1.f;
        float2 s = {0.f, 0.f};
        #pragma unroll
        for (int gg = 0; gg < 10; ++gg) {
            float2 ua = uurow[gg], ub = uurow[gg + 10];
            float ux = ua.x + sgn * ub.x, uy = ua.y + sgn * ub.y;
            float2 e = FF2s[ni * 20 + gg];
            s.x += ux * e.x - uy * e.y;
            s.y += ux * e.y + uy * e.x;
        }
        ymnA[i] = s;
    }
    __syncthreads();

    // (e) per-lane acc over all 20 k + packed write
    for (int v = tid; v < 286; v += 256) {
        int w = VTAB[v];
        int l = w & 15, m = (w >> 4) & 15, n = (w >> 8) & 15;
        int fidx = l * 121 + m * 11 + n;
        int off; float sy;
        if (m >= 5) { off = (m - 5) * 11 + n; sy = 1.f; }
        else        { off = (5 - m) * 11 + (10 - n); sy = -1.f; }
        float2 s = {0.f, 0.f};
        for (int k = 0; k < 20; ++k) {
            float wv = WS3[k * 726 + fidx];
            float2 ym = ymnA[k * 66 + off];
            s.x += wv * ym.x;
            s.y += wv * sy * ym.y;
        }
        X2g[v] = s;
    }
}

// ---------------------------------------------------------------------------
// stage2 v10: v9 + DOUBLE-BUFFERED phase A (1 barrier/iter, loads for i+1 in
// registers during compute of i — global latency off the critical path; v9
// had 2 barriers x 20 iters with exposed L2 latency each) + z2 rebuild
// restricted to rows m>=5 (phase C reads only those): 726 -> 396 items.
// LDS 27.6 KB -> 5 blocks/CU.
// ---------------------------------------------------------------------------
__global__ __launch_bounds__(256) void stage2_kernel(float* ws) {
    const int tid = threadIdx.x;
    const int wave = tid >> 6, lane = tid & 63;
    const int b  = blockIdx.x / 10;
    const int og = blockIdx.x % 10;
    const int o0 = og * 4;
    const float2* X2p = (const float2*)(ws + OFF_X2P) + b * 20 * 286;
    const float2* P2p = (const float2*)(ws + OFF_PSI2P);
    const float*  WI2 = ws + OFF_WINV2;
    const float2* EA2 = (const float2*)(ws + OFF_EA2);
    const float*  WIT = ws + OFF_WINT;
    const int*  VTAB2 = (const int*)(ws + OFF_VTAB2);
    float* featg = ws + OFF_FEAT;

    // LDS (floats): P partials [0..1168) (4 x 146 f2, live past phase A);
    //   bufA [1168..4028), bufB [4028..6888): 715 f4 each (xi 143 | pp 4x143)
    //   phases B/C alias bufA: z2s 396 f2 [1168..1960), fh2 792 f2
    //   [1960..3544), t2 864 f2 [3544..5272)
    __shared__ float sm[6888];
    __shared__ float red[4];

    int xo[3], po[3], klen[3];
    float2 acc[3];
    #pragma unroll
    for (int t = 0; t < 3; ++t) {
        int v = lane + 64 * t;
        acc[t] = make_float2(0.f, 0.f);
        if (v < 146) {
            int w = VTAB2[v];
            int l = w & 15, dm = ((w >> 4) & 15) - 5, dn = ((w >> 8) & 15) - 5;
            int base = l * (4 * l * l - 1) / 3, span = 2 * l + 1;
            xo[t] = base + (dm + l) * span;
            po[t] = base + (dn + l) * span;
            klen[t] = span;
        } else { xo[t] = 0; po[t] = 0; klen[t] = 0; }
    }

    // per-thread staging slots (715 f4 over 256 threads -> 3 slots)
    int sv[3], sarr[3], sidx[3];
    #pragma unroll
    for (int t = 0; t < 3; ++t) {
        sv[t] = tid + 256 * t;
        sarr[t] = sv[t] / 143; sidx[t] = sv[t] - sarr[t] * 143;
    }
    float4 rg[3];

    // phase A: double-buffered i-loop; wave w computes o = o0+w
    #define LOAD_I(i)                                                          \
        { _Pragma("unroll")                                                    \
          for (int t = 0; t < 3; ++t) if (sv[t] < 715) {                       \
              const float4* src = (sarr[t] == 0)                               \
                  ? (const float4*)(X2p + (i) * 286)                           \
                  : (const float4*)(P2p + ((i) * 40 + o0 + (sarr[t] - 1)) * 286); \
              rg[t] = src[sidx[t]];                                            \
          } }
    #define STORE_BUF(ph)                                                      \
        { float4* B = (float4*)(sm + ((ph) ? 4028 : 1168)); _Pragma("unroll")  \
          for (int t = 0; t < 3; ++t) if (sv[t] < 715) B[sidx[t] + sarr[t] * 143] = rg[t]; }

    LOAD_I(0)
    STORE_BUF(0)
    __syncthreads();
    for (int i = 0; i < 20; ++i) {
        if (i < 19) LOAD_I(i + 1)
        const float* base = sm + ((i & 1) ? 4028 : 1168);
        const float2* xiW = (const float2*)base;
        const float2* ppW = (const float2*)(base + 572 + wave * 572);
        #pragma unroll
        for (int t = 0; t < 3; ++t) {
            for (int k = 0; k < klen[t]; ++k) {
                float2 u = xiW[xo[t] + k], v2 = ppW[po[t] + k];
                acc[t].x += u.x * v2.x + u.y * v2.y;
                acc[t].y += u.y * v2.x - u.x * v2.y;
            }
        }
        if (i < 19) STORE_BUF((i + 1) & 1)
        __syncthreads();
    }
    #undef LOAD_I
    #undef STORE_BUF

    // write complete per-o partials
    float2* P = (float2*)sm;   // [4][146]
    #pragma unroll
    for (int t = 0; t < 3; ++t) {
        int v = lane + 64 * t;
        if (v < 146) P[wave * 146 + v] = acc[t];
    }
    __syncthreads();

    // phases B/C per oL
    float2* z2s = (float2*)(sm + 1168);   // [6 l][6 m>=5][11 n]
    float2* fh2 = (float2*)(sm + 1960);
    float2* t2  = (float2*)(sm + 3544);
    for (int oL = 0; oL < 4; ++oL) {
        // B: rebuild z2 rows m>=5 only (phase C reads nothing else)
        for (int idx = tid; idx < 396; idx += 256) {
            int ll = idx / 66, rr = idx - ll * 66, dm = rr / 11, n = rr - dm * 11;
            int dn = n - 5;
            int an = dn < 0 ? -dn : dn;
            float2 s = {0.f, 0.f};
            if (dm <= ll && an <= ll) {
                bool inhalf = (dm > 0) || (dm == 0 && dn >= 0);
                int ddm = inhalf ? dm : -dm, ddn = inhalf ? dn : -dn;
                int lp = ll + 1;
                int st = 146 - lp * (2 * lp * lp + 1) / 3;
                int h = st + (ddm == 0 ? ddn : (ll + 1) + (ddm - 1) * (2 * ll + 1) + (ddn + ll));
                s = P[oL * 146 + h];
                if (!inhalf) {
                    float sign = ((dm + an) & 1) ? -1.f : 1.f;
                    s = make_float2(sign * s.x, -sign * s.y);
                }
            }
            z2s[idx] = s;
        }
        __syncthreads();
        // C: fh2 rows m>=5, all 12 k2
        for (int i = tid; i < 792; i += 256) {
            int k2 = i / 66, rr = i - k2 * 66;
            int mrow = rr / 11, n = rr - mrow * 11;
            int dn = n - 5, an = dn < 0 ? -dn : dn;
            int lmin = mrow > an ? mrow : an;
            int mfull = mrow + 5;
            float2 s = {0.f, 0.f};
            for (int ll = lmin; ll < 6; ++ll) {
                float w = WI2[k2 * 726 + ll * 121 + mfull * 11 + n];
                float2 z = z2s[ll * 66 + mrow * 11 + n];
                s.x += w * z.x; s.y += w * z.y;
            }
            fh2[i] = s;
        }
        __syncthreads();
        for (int i = tid; i < 864; i += 256) {
            int k2 = i / 72, rr = i - k2 * 72, mrow = rr / 12, g = rr - mrow * 12;
            float2 s = {0.f, 0.f};
            #pragma unroll
            for (int n = 0; n < 11; ++n) {
                float2 f = fh2[k2 * 66 + mrow * 11 + n], e = EA2[n * 12 + g];
                s.x += f.x * e.x - f.y * e.y;
                s.y += f.x * e.y + f.y * e.x;
            }
            t2[i] = s;
        }
        __syncthreads();
        float partial = 0.f;
        for (int i = tid; i < 864; i += 256) {
            int k2 = i / 72, rr = i - k2 * 72, a = rr / 12, g = rr - a * 12;
            float base = t2[k2 * 72 + g].x;
            float se = 0.f, so = 0.f;
            #pragma unroll
            for (int d = 1; d < 6; ++d) {
                float2 e = EA2[(5 + d) * 12 + a];
                float2 t = t2[k2 * 72 + d * 12 + g];
                float c = 2.f * (e.x * t.x - e.y * t.y);
                if (d & 1) so += c; else se += c;
            }
            float y0 = base + se + so, y1 = base + se - so;
            float w = WIT[k2];
            if (y0 > 0.f) partial += w * y0;
            if (y1 > 0.f) partial += w * y1;
        }
        for (int off = 32; off > 0; off >>= 1) partial += __shfl_down(partial, off, 64);
        if ((tid & 63) == 0) red[tid >> 6] = partial;
        __syncthreads();
        if (tid == 0) featg[b * 40 + o0 + oL] =
            (red[0] + red[1] + red[2] + red[3]) * (1.0f / 144.0f);
        __syncthreads();
    }
}

// ---------------------------------------------------------------------------
__global__ __launch_bounds__(256) void final_kernel(const float* __restrict__ ws,
                                                    const float* __restrict__ wl,
                                                    const float* __restrict__ bl,
                                                    float* __restrict__ out) {
    int idx = blockIdx.x * 256 + threadIdx.x;
    if (idx >= 1280) return;
    int b = idx / 10, f = idx % 10;
    const float* feat = ws + OFF_FEAT;
    float s = bl[f];
    for (int o = 0; o < 40; ++o) s += feat[b * 40 + o] * wl[f * 40 + o];
    out[idx] = s;
}

// ---------------------------------------------------------------------------
extern "C" void kernel_launch(void* const* d_in, const int* in_sizes, int n_in,
                              void* d_out, int out_size, void* d_ws, size_t ws_size,
                              hipStream_t stream) {
    (void)in_sizes; (void)n_in; (void)out_size; (void)ws_size;
    const float* x  = (const float*)d_in[0];
    const float* k1 = (const float*)d_in[1];
    const float* k2 = (const float*)d_in[2];
    const float* wl = (const float*)d_in[3];
    const float* bl = (const float*)d_in[4];
    float* out = (float*)d_out;
    float* ws  = (float*)d_ws;

    build_tables_kernel<<<829, 256, 0, stream>>>(ws);
    prep_kernel<<<600, 256, 0, stream>>>(ws, k1, k2, x);
    stage1_kernel<<<128 * 20, 256, 0, stream>>>(
        ws + OFF_WINV1, ws + OFF_WSO3, ws + OFF_EA1, ws + OFF_FF2,
        (const float2*)(ws + OFF_X), (const float2*)(ws + OFF_PSI),
        (const int*)(ws + OFF_VTAB), (float2*)(ws + OFF_X2P));
    stage2_kernel<<<128 * 10, 256, 0, stream>>>(ws);
    final_kernel<<<5, 256, 0, stream>>>(ws, wl, bl, out);
}

// Round 15
// 328.006 us; speedup vs baseline: 1.0553x; 1.0553x over previous
//
#include <hip/hip_runtime.h>
#include <math.h>

// ---------------------------------------------------------------------------
// Problem dims: B_IN=15, B1=10, B2=6, F1=20, F2=40, F_OUT=10
// M1=19, C1=9, M2=11, C2=5, batch=128
// VALID(l,m,n): |m-5|<=l && |n-5|<=l -> 286 of 726; packed base(l)=l(4l^2-1)/3
// HALF set (z2 Hermitian): dm>0 or (dm==0 && dn>=0) -> 146, l-DESCENDING.
// Parity identities (exact):
//   E_A1[mi, a+10] = (-1)^(mi-9) E_A1[mi, a]
//   E_A1[n,  g+10] = (-1)^(n-9)  E_A1[n,  g]   (g-pair fold)
//   FF2[5+d, a+10] = (-1)^d FF2[5+d, a]
//   FF2[ni,  g+10] = (-1)^(ni-5) FF2[ni, g]    (ymn g-fold)
//   E_A2[5+d, a+6] = (-1)^d E_A2[5+d, a]
//   ymn[10-mi,10-ni] = conj(ymn[mi,ni])        (y real)
// ---------------------------------------------------------------------------

constexpr int OFF_WS2   = 0;                      // W_S2_FWD  [30][10][19]
constexpr int OFF_WINV1 = OFF_WS2   + 5700;       // W_INV1    [20][10][19][19] (m>=9 rows only built)
constexpr int OFF_WSO3  = OFF_WINV1 + 72200;      // W_SO3_FWD [20][6][11][11]
constexpr int OFF_WINV2 = OFF_WSO3  + 14520;      // W_INV2    [12][6][11][11] (m>=5 rows only built)
constexpr int OFF_WINT  = OFF_WINV2 + 8712;       // W_INT     [12] (+pad)
constexpr int OFF_FE1   = OFF_WINT  + 16;         // FE1  cplx [19][30]
constexpr int OFF_EA1   = OFF_FE1   + 1140;       // E_A1 cplx [19][20]
constexpr int OFF_FF2   = OFF_EA1   + 760;        // FF2  cplx [11][20]
constexpr int OFF_EA2   = OFF_FF2   + 440;        // E_A2 cplx [11][12]
constexpr int OFF_BS2   = OFF_EA2   + 264;        // B_S2 cplx [24][10][19]
constexpr int OFF_BSO3  = OFF_BS2   + 9120;       // B_SO3 cplx[144][6][11][11] (half-set only built)
constexpr int OFF_PSI   = OFF_BSO3  + 209088;     // psi  cplx [20][10][19]
constexpr int OFF_X     = OFF_PSI   + 7600;       // X    cplx [128][10][19]
constexpr int OFF_X2P   = OFF_X     + 48640;      // X2 packed [128][20][286] cplx
constexpr int OFF_PSI2P = OFF_X2P   + 1464320;    // psi2 packed [20][40][286] cplx
constexpr int OFF_FEAT  = OFF_PSI2P + 457600;     // feat      [128][40]
constexpr int OFF_VTAB  = OFF_FEAT  + 5120;       // int[286] valid (l,m,n)
constexpr int OFF_VTAB2 = OFF_VTAB  + 286;        // int[146] half-set, l desc

#define DPI 3.14159265358979323846

// ---------------------------------------------------------------------------
__device__ __forceinline__ double dfact(int n) {
    double f = 1.0;
    for (int i = 2; i <= n; ++i) f *= (double)i;
    return f;
}
__device__ __forceinline__ double dpowi(double x, int n) {
    double r = 1.0;
    for (int i = 0; i < n; ++i) r *= x;
    return r;
}
__device__ double wig_d(int l, int mi, int ni, double beta) {
    int m = mi - l, n = ni - l;
    double cb = cos(0.5 * beta), sb = sin(0.5 * beta);
    double pref = sqrt(dfact(l + m) * dfact(l - m) * dfact(l + n) * dfact(l - n));
    int s0 = (n - m) > 0 ? (n - m) : 0;
    int s1 = (l + n) < (l - m) ? (l + n) : (l - m);
    double v = 0.0;
    for (int s = s0; s <= s1; ++s) {
        double term = dpowi(cb, 2 * l + n - m - 2 * s) * dpowi(sb, m - n + 2 * s) /
                      (dfact(l + n - s) * dfact(s) * dfact(m - n + s) * dfact(l - m - s));
        v += ((m - n + s) & 1) ? -term : term;
    }
    return pref * v;
}
__device__ double wig_pad(int l, int m, int n, int c, double beta) {
    if (m < c - l || m > c + l || n < c - l || n > c + l) return 0.0;
    return wig_d(l, m - (c - l), n - (c - l), beta);
}
__device__ double quad_w(int b, int k) {
    double beta = DPI * (2 * k + 1) / (4.0 * b);
    double s = 0.0;
    for (int j = 0; j < b; ++j) s += sin((2 * j + 1) * beta) / (double)(2 * j + 1);
    return 2.0 / b * sin(beta) * s;
}

// element ids total = 211982 (unread entries skipped)
__global__ __launch_bounds__(256) void build_tables_kernel(float* ws) {
    int idx = blockIdx.x * 256 + threadIdx.x;
    if (idx < 5700) {
        int k = idx / 190, r = idx % 190, l = r / 19, m = r % 19;
        double beta = DPI * (2 * k + 1) / 60.0;
        ws[OFF_WS2 + idx] = (float)(quad_w(15, k) * wig_pad(l, m, 9, 9, beta));
        return;
    }
    idx -= 5700;
    if (idx < 72200) {
        int k = idx / 3610, r = idx % 3610, l = r / 361, r2 = r % 361, m = r2 / 19, n = r2 % 19;
        if (m < 9) return;   // stage1 reads only mi>=9 rows
        double beta = DPI * (2 * k + 1) / 40.0;
        ws[OFF_WINV1 + idx] = (float)((2 * l + 1) * wig_pad(l, m, n, 9, beta));
        return;
    }
    idx -= 72200;
    if (idx < 14520) {
        int k = idx / 726, r = idx % 726, l = r / 121, m = (r % 121) / 11, n = r % 11;
        double beta = DPI * (2 * k + 1) / 40.0;
        ws[OFF_WSO3 + idx] = (float)(quad_w(10, k) * wig_pad(l, m, n, 5, beta));
        return;
    }
    idx -= 14520;
    if (idx < 8712) {
        int k = idx / 726, r = idx % 726, l = r / 121, m = (r % 121) / 11, n = r % 11;
        if (m < 5) return;   // stage2 phase C reads only m>=5 rows
        double beta = DPI * (2 * k + 1) / 24.0;
        ws[OFF_WINV2 + idx] = (float)((2 * l + 1) * wig_pad(l, m, n, 5, beta));
        return;
    }
    idx -= 8712;
    if (idx < 12) { ws[OFF_WINT + idx] = (float)quad_w(6, idx); return; }
    idx -= 12;
    if (idx < 570) {
        int m = idx / 30, t = idx % 30;
        double ang = -2.0 * DPI * (double)((m - 9) * t) / 30.0;
        ws[OFF_FE1 + 2 * idx] = (float)cos(ang);
        ws[OFF_FE1 + 2 * idx + 1] = (float)sin(ang);
        return;
    }
    idx -= 570;
    if (idx < 380) {
        int m = idx / 20, a = idx % 20;
        double ang = 2.0 * DPI * (double)((m - 9) * a) / 20.0;
        ws[OFF_EA1 + 2 * idx] = (float)cos(ang);
        ws[OFF_EA1 + 2 * idx + 1] = (float)sin(ang);
        return;
    }
    idx -= 380;
    if (idx < 220) {
        int m = idx / 20, a = idx % 20;
        double ang = -2.0 * DPI * (double)((m - 5) * a) / 20.0;
        ws[OFF_FF2 + 2 * idx] = (float)cos(ang);
        ws[OFF_FF2 + 2 * idx + 1] = (float)sin(ang);
        return;
    }
    idx -= 220;
    if (idx < 132) {
        int m = idx / 12, a = idx % 12;
        double ang = 2.0 * DPI * (double)((m - 5) * a) / 12.0;
        ws[OFF_EA2 + 2 * idx] = (float)cos(ang);
        ws[OFF_EA2 + 2 * idx + 1] = (float)sin(ang);
        return;
    }
    idx -= 132;
    if (idx < 4560) {
        int p = idx / 190, r = idx % 190, l = r / 19, m = r % 19;
        int bi = p / 8, ai = p % 8;
        double beta = (bi + 1) * (DPI / 24.0);
        double alpha = 2.0 * DPI * ai / 8.0;
        double re = 0.0, im = 0.0;
        if (m - 9 >= -l && m - 9 <= l) {
            double d = wig_d(l, m - 9 + l, l, beta);
            double ang = -(double)(m - 9) * alpha;
            re = d * cos(ang); im = d * sin(ang);
        }
        ws[OFF_BS2 + 2 * idx] = (float)re;
        ws[OFF_BS2 + 2 * idx + 1] = (float)im;
        return;
    }
    idx -= 4560;
    if (idx < 104544) {
        int p = idx / 726, r = idx % 726, l = r / 121, m = (r % 121) / 11, n = r % 11;
        int dm = m - 5, dn = n - 5;
        int am = dm < 0 ? -dm : dm, an = dn < 0 ? -dn : dn;
        if (am > l || an > l) return;                       // structurally zero
        if (!((dm > 0) || (dm == 0 && dn >= 0))) return;    // psi2 reads half-set only
        int bi = p / 48, ai = (p % 48) / 6, gi = p % 6;
        double beta = (bi + 1) * (DPI / 24.0);
        double alpha = 2.0 * DPI * ai / 8.0;
        double gamma = 2.0 * DPI * gi / 6.0;
        double d = wig_d(l, m - 5 + l, n - 5 + l, beta);
        double ang = -((double)(m - 5) * alpha + (double)(n - 5) * gamma);
        ws[OFF_BSO3 + 2 * idx] = (float)(d * cos(ang));
        ws[OFF_BSO3 + 2 * idx + 1] = (float)(d * sin(ang));
        return;
    }
    idx -= 104544;
    if (idx < 286) {
        int l = 0, cum = 0;
        while (idx >= cum + (2 * l + 1) * (2 * l + 1)) { cum += (2 * l + 1) * (2 * l + 1); ++l; }
        int rem = idx - cum, w = 2 * l + 1;
        int m = 5 - l + rem / w, n = 5 - l + rem % w;
        ((int*)(ws + OFF_VTAB))[idx] = l | (m << 4) | (n << 8);
        return;
    }
    idx -= 286;
    if (idx < 146) {
        int l = 5, st = 0;
        while (idx >= st + (2 * l * l + 2 * l + 1)) { st += 2 * l * l + 2 * l + 1; --l; }
        int rem = idx - st;
        int dm, dn;
        if (rem < l + 1) { dm = 0; dn = rem; }
        else { int r2 = rem - (l + 1); dm = 1 + r2 / (2 * l + 1); dn = r2 % (2 * l + 1) - l; }
        ((int*)(ws + OFF_VTAB2))[idx] = l | ((dm + 5) << 4) | ((dn + 5) << 8);
        return;
    }
}

// ---------------------------------------------------------------------------
// prep_kernel: psi2 (blocks 0..456) + xform1 (457..584) + psi1 (585..599)
// ---------------------------------------------------------------------------
__global__ __launch_bounds__(256) void prep_kernel(float* ws,
                                                   const float* __restrict__ k1,
                                                   const float* __restrict__ k2,
                                                   const float* __restrict__ x) {
    const int bid = blockIdx.x, tid = threadIdx.x;
    __shared__ float xs[900];
    __shared__ float2 xm[570];

    if (bid < 457) {
        int idx = bid * 256 + tid;
        if (idx >= 116800) return;
        int i = idx / 5840, r = idx % 5840, o = r / 146, h = r % 146;
        int w = ((const int*)(ws + OFF_VTAB2))[h];
        int l = w & 15, dm = ((w >> 4) & 15) - 5, dn = ((w >> 8) & 15) - 5;
        int lmn = l * 121 + (dm + 5) * 11 + (dn + 5);
        const float2* BS = (const float2*)(ws + OFF_BSO3);
        float2 s = {0.f, 0.f};
        for (int p = 0; p < 144; ++p) {
            float wv = k2[(i * 40 + o) * 144 + p];
            float2 bv = BS[p * 726 + lmn];
            s.x += wv * bv.x; s.y += wv * bv.y;
        }
        float2* row = (float2*)(ws + OFF_PSI2P) + (i * 40 + o) * 286;
        int base = l * (4 * l * l - 1) / 3, span = 2 * l + 1;
        row[base + (dm + l) * span + (dn + l)] = s;
        float sign = ((dm + dn + 16) & 1) ? -1.f : 1.f;
        row[base + (-dm + l) * span + (-dn + l)] = make_float2(sign * s.x, -sign * s.y);
        return;
    }
    if (bid < 585) {
        const int b = bid - 457;
        const float2* FE1 = (const float2*)(ws + OFF_FE1);
        const float* WS2 = ws + OFF_WS2;
        float2* Xg = (float2*)(ws + OFF_X) + b * 190;
        for (int i = tid; i < 900; i += 256) xs[i] = x[b * 900 + i];
        __syncthreads();
        for (int i = tid; i < 570; i += 256) {
            int k = i / 19, m = i % 19;
            float2 s = {0.f, 0.f};
            #pragma unroll
            for (int t = 0; t < 30; ++t) {
                float v = xs[k * 30 + t];
                float2 e = FE1[m * 30 + t];
                s.x += v * e.x; s.y += v * e.y;
            }
            xm[k * 19 + m] = s;
        }
        __syncthreads();
        for (int i = tid; i < 190; i += 256) {
            int l = i / 19, m = i % 19;
            float2 s = {0.f, 0.f};
            for (int k = 0; k < 30; ++k) {
                float w = WS2[k * 190 + l * 19 + m];
                float2 v = xm[k * 19 + m];
                s.x += w * v.x; s.y += w * v.y;
            }
            Xg[i] = s;
        }
        return;
    }
    {
        int idx = (bid - 585) * 256 + tid;
        if (idx >= 3800) return;
        int o = idx / 190, r = idx % 190;
        const float2* BS2 = (const float2*)(ws + OFF_BS2);
        float2 s = {0.f, 0.f};
        for (int p = 0; p < 24; ++p) {
            float w = k1[o * 24 + p];
            float2 bv = BS2[p * 190 + r];
            s.x += w * bv.x; s.y += w * bv.y;
        }
        ((float2*)(ws + OFF_PSI))[idx] = s;
    }
}

// ---------------------------------------------------------------------------
// stage1 v10 (unchanged, r13-validated)
// ---------------------------------------------------------------------------
__global__ __launch_bounds__(256, 3) void stage1_kernel(
    const float* __restrict__ WI1, const float* __restrict__ WS3,
    const float* __restrict__ EA1, const float* __restrict__ FF2,
    const float2* __restrict__ Xall, const float2* __restrict__ Pall,
    const int* __restrict__ VTAB, float2* __restrict__ X2out)
{
    const int tid = threadIdx.x;
    const int b = blockIdx.x / 20;
    const int o = blockIdx.x % 20;
    const float2* Xg = Xall + b * 190;
    const float2* Pg = Pall + o * 190;
    float2* X2g = X2out + (b * 20 + o) * 286;
    const float2* EA1c = (const float2*)EA1;
    const float2* FF2c = (const float2*)FF2;

    __shared__ float2 Xs[190], Ps[190], FF2s[220];
    __shared__ float2 fhA[3800];
    __shared__ float2 ymnA[1320];

    const int gpair = tid % 10;
    const int kk = tid / 10;
    const bool active = (tid < 200);

    float2 eg[19];
    #pragma unroll
    for (int n = 0; n < 19; ++n) eg[n] = EA1c[n * 20 + gpair];

    for (int i = tid; i < 190; i += 256) { Xs[i] = Xg[i]; Ps[i] = Pg[i]; }
    for (int i = tid; i < 220; i += 256) FF2s[i] = FF2c[i];
    __syncthreads();

    // (a) fh build block-wide
    for (int i = tid; i < 3800; i += 256) {
        int k = i / 190, idx = i - k * 190;
        int mrow = idx / 19, ni = idx - mrow * 19;
        int mi = mrow + 9;
        int an = ni > 9 ? ni - 9 : 9 - ni;
        int lmin = mrow > an ? mrow : an;
        const float* wk = WI1 + k * 3610 + mi * 19 + ni;
        float2 s = {0.f, 0.f};
        for (int l = lmin; l < 10; ++l) {
            float2 a = Xs[l * 19 + mi], c = Ps[l * 19 + ni];
            float wv = wk[l * 361];
            s.x += wv * (a.x * c.x + a.y * c.y);
            s.y += wv * (a.y * c.x - a.x * c.y);
        }
        fhA[i] = s;
    }
    __syncthreads();

    // (b) per-lane column-PAIR pipeline
    float2 uacc0[6], uacc1[6];
    if (active) {
        const float2* fhk = fhA + kk * 190;
        float ye0[10], yo0[10], ye1[10], yo1[10];
        {
            float2 te = {0.f, 0.f}, to = {0.f, 0.f};
            #pragma unroll
            for (int n = 0; n < 19; ++n) {
                float2 f = fhk[n];
                float rx = f.x * eg[n].x - f.y * eg[n].y;
                float ry = f.x * eg[n].y + f.y * eg[n].x;
                if (n & 1) { te.x += rx; te.y += ry; }
                else       { to.x += rx; to.y += ry; }
            }
            float t0x = te.x + to.x, t1x = te.x - to.x;
            #pragma unroll
            for (int a = 0; a < 10; ++a) {
                ye0[a] = t0x; yo0[a] = 0.f;
                ye1[a] = t1x; yo1[a] = 0.f;
            }
        }
        #pragma unroll 1   // r7 lesson: full unroll -> VGPR cliff
        for (int mrow = 1; mrow < 10; ++mrow) {
            float2 te = {0.f, 0.f}, to = {0.f, 0.f};
            #pragma unroll
            for (int n = 0; n < 19; ++n) {
                float2 f = fhk[mrow * 19 + n];
                float rx = f.x * eg[n].x - f.y * eg[n].y;
                float ry = f.x * eg[n].y + f.y * eg[n].x;
                if (n & 1) { te.x += rx; te.y += ry; }
                else       { to.x += rx; to.y += ry; }
            }
            float2 t0 = make_float2(2.f * (te.x + to.x), 2.f * (te.y + to.y));
            float2 t1 = make_float2(2.f * (te.x - to.x), 2.f * (te.y - to.y));
            if (mrow & 1) {
                #pragma unroll
                for (int a = 0; a < 10; ++a) {
                    float2 e = EA1c[(9 + mrow) * 20 + a];
                    yo0[a] += t0.x * e.x - t0.y * e.y;
                    yo1[a] += t1.x * e.x - t1.y * e.y;
                }
            } else {
                #pragma unroll
                for (int a = 0; a < 10; ++a) {
                    float2 e = EA1c[(9 + mrow) * 20 + a];
                    ye0[a] += t0.x * e.x - t0.y * e.y;
                    ye1[a] += t1.x * e.x - t1.y * e.y;
                }
            }
        }
        #pragma unroll
        for (int a = 0; a < 10; ++a) {
            float p0 = ye0[a] + yo0[a]; p0 = p0 > 0.f ? p0 : 0.f;
            float q0 = ye0[a] - yo0[a]; q0 = q0 > 0.f ? q0 : 0.f;
            ye0[a] = p0 + q0; yo0[a] = p0 - q0;
            float p1 = ye1[a] + yo1[a]; p1 = p1 > 0.f ? p1 : 0.f;
            float q1 = ye1[a] - yo1[a]; q1 = q1 > 0.f ? q1 : 0.f;
            ye1[a] = p1 + q1; yo1[a] = p1 - q1;
        }
        uacc0[0] = make_float2(0.f, 0.f); uacc1[0] = make_float2(0.f, 0.f);
        #pragma unroll
        for (int a = 0; a < 10; ++a) { uacc0[0].x += ye0[a]; uacc1[0].x += ye1[a]; }
        #pragma unroll
        for (int d = 1; d < 6; ++d) {
            uacc0[d] = make_float2(0.f, 0.f); uacc1[d] = make_float2(0.f, 0.f);
            #pragma unroll
            for (int a = 0; a < 10; ++a) {
                float q0 = (d & 1) ? yo0[a] : ye0[a];
                float q1 = (d & 1) ? yo1[a] : ye1[a];
                float2 e = FF2c[(5 + d) * 20 + a];
                uacc0[d].x += e.x * q0; uacc0[d].y += e.y * q0;
                uacc1[d].x += e.x * q1; uacc1[d].y += e.y * q1;
            }
        }
    }
    __syncthreads();

    // (c) uu compact write [k][6][20], aliases fhA
    float2* uubuf = fhA;
    if (active) {
        #pragma unroll
        for (int d = 0; d < 6; ++d) {
            uubuf[kk * 120 + d * 20 + gpair]      = uacc0[d];
            uubuf[kk * 120 + d * 20 + gpair + 10] = uacc1[d];
        }
    }
    __syncthreads();

    // (d) ymn rows mi=5..10, g-FOLDED
    for (int i = tid; i < 1320; i += 256) {
        int k = i / 66, rr = i - k * 66;
        int d = rr / 11, ni = rr - d * 11;
        const float2* uurow = uubuf + k * 120 + d * 20;
        float sgn = (ni & 1) ? 1.f : -1.f;
        float2 s = {0.f, 0.f};
        #pragma unroll
        for (int gg = 0; gg < 10; ++gg) {
            float2 ua = uurow[gg], ub = uurow[gg + 10];
            float ux = ua.x + sgn * ub.x, uy = ua.y + sgn * ub.y;
            float2 e = FF2s[ni * 20 + gg];
            s.x += ux * e.x - uy * e.y;
            s.y += ux * e.y + uy * e.x;
        }
        ymnA[i] = s;
    }
    __syncthreads();

    // (e) per-lane acc over all 20 k + packed write
    for (int v = tid; v < 286; v += 256) {
        int w = VTAB[v];
        int l = w & 15, m = (w >> 4) & 15, n = (w >> 8) & 15;
        int fidx = l * 121 + m * 11 + n;
        int off; float sy;
        if (m >= 5) { off = (m - 5) * 11 + n; sy = 1.f; }
        else        { off = (5 - m) * 11 + (10 - n); sy = -1.f; }
        float2 s = {0.f, 0.f};
        for (int k = 0; k < 20; ++k) {
            float wv = WS3[k * 726 + fidx];
            float2 ym = ymnA[k * 66 + off];
            s.x += wv * ym.x;
            s.y += wv * sy * ym.y;
        }
        X2g[v] = s;
    }
}

// ---------------------------------------------------------------------------
// stage2 v11 = r13-validated v9 phase A (single buffer, direct global->LDS,
// NO register staging — v10's rg[] prefetch spilled to scratch: 164 MB
// WRITE_SIZE, 152us) + r14's trimmed phases B/C (z2 rebuild m>=5 rows only,
// 396 items, compact [l][6][11] layout). LDS 21.1 KB -> 6+ blocks/CU.
// ---------------------------------------------------------------------------
__global__ __launch_bounds__(256) void stage2_kernel(float* ws) {
    const int tid = threadIdx.x;
    const int wave = tid >> 6, lane = tid & 63;
    const int b  = blockIdx.x / 10;
    const int og = blockIdx.x % 10;
    const int o0 = og * 4;
    const float2* X2p = (const float2*)(ws + OFF_X2P) + b * 20 * 286;
    const float2* P2p = (const float2*)(ws + OFF_PSI2P);
    const float*  WI2 = ws + OFF_WINV2;
    const float2* EA2 = (const float2*)(ws + OFF_EA2);
    const float*  WIT = ws + OFF_WINT;
    const int*  VTAB2 = (const int*)(ws + OFF_VTAB2);
    float* featg = ws + OFF_FEAT;

    // LDS (floats): P partials [0..1168) (4 x 146 f2, live past phase A);
    //   phase A buffer at 1168: 715 f4 = 2860 f (xi 143 f4 | pp 4x143 f4)
    //   phases B/C alias: z2s 396 f2 [1168..1960), fh2 792 f2 [1960..3544),
    //   t2 864 f2 [3544..5272)
    __shared__ float sm[5272];
    __shared__ float red[4];

    int xo[3], po[3], klen[3];
    float2 acc[3];
    #pragma unroll
    for (int t = 0; t < 3; ++t) {
        int v = lane + 64 * t;
        acc[t] = make_float2(0.f, 0.f);
        if (v < 146) {
            int w = VTAB2[v];
            int l = w & 15, dm = ((w >> 4) & 15) - 5, dn = ((w >> 8) & 15) - 5;
            int base = l * (4 * l * l - 1) / 3, span = 2 * l + 1;
            xo[t] = base + (dm + l) * span;
            po[t] = base + (dn + l) * span;
            klen[t] = span;
        } else { xo[t] = 0; po[t] = 0; klen[t] = 0; }
    }

    // phase A: block-wide staged i-loop (r13-validated); wave w -> o = o0+w
    float4* A4 = (float4*)(sm + 1168);
    const float2* xiW = (const float2*)(sm + 1168);
    const float2* ppW = (const float2*)(sm + 1168 + 572 + wave * 572);
    for (int i = 0; i < 20; ++i) {
        __syncthreads();   // prior-iter reads done before overwrite
        for (int v = tid; v < 715; v += 256) {
            int arr = v / 143, idx = v - arr * 143;
            const float4* src = (arr == 0)
                ? (const float4*)(X2p + i * 286)
                : (const float4*)(P2p + (i * 40 + o0 + (arr - 1)) * 286);
            A4[v] = src[idx];
        }
        __syncthreads();
        #pragma unroll
        for (int t = 0; t < 3; ++t) {
            for (int k = 0; k < klen[t]; ++k) {
                float2 u = xiW[xo[t] + k], v2 = ppW[po[t] + k];
                acc[t].x += u.x * v2.x + u.y * v2.y;
                acc[t].y += u.y * v2.x - u.x * v2.y;
            }
        }
    }
    __syncthreads();

    // write complete per-o partials
    float2* P = (float2*)sm;   // [4][146]
    #pragma unroll
    for (int t = 0; t < 3; ++t) {
        int v = lane + 64 * t;
        if (v < 146) P[wave * 146 + v] = acc[t];
    }
    __syncthreads();

    // phases B/C per oL
    float2* z2s = (float2*)(sm + 1168);   // [6 l][6 m>=5][11 n]
    float2* fh2 = (float2*)(sm + 1960);
    float2* t2  = (float2*)(sm + 3544);
    for (int oL = 0; oL < 4; ++oL) {
        // B: rebuild z2 rows m>=5 only (phase C reads nothing else)
        for (int idx = tid; idx < 396; idx += 256) {
            int ll = idx / 66, rr = idx - ll * 66, dm = rr / 11, n = rr - dm * 11;
            int dn = n - 5;
            int an = dn < 0 ? -dn : dn;
            float2 s = {0.f, 0.f};
            if (dm <= ll && an <= ll) {
                bool inhalf = (dm > 0) || (dm == 0 && dn >= 0);
                int ddm = inhalf ? dm : -dm, ddn = inhalf ? dn : -dn;
                int lp = ll + 1;
                int st = 146 - lp * (2 * lp * lp + 1) / 3;
                int h = st + (ddm == 0 ? ddn : (ll + 1) + (ddm - 1) * (2 * ll + 1) + (ddn + ll));
                s = P[oL * 146 + h];
                if (!inhalf) {
                    float sign = ((dm + an) & 1) ? -1.f : 1.f;
                    s = make_float2(sign * s.x, -sign * s.y);
                }
            }
            z2s[idx] = s;
        }
        __syncthreads();
        // C: fh2 rows m>=5, all 12 k2
        for (int i = tid; i < 792; i += 256) {
            int k2 = i / 66, rr = i - k2 * 66;
            int mrow = rr / 11, n = rr - mrow * 11;
            int dn = n - 5, an = dn < 0 ? -dn : dn;
            int lmin = mrow > an ? mrow : an;
            int mfull = mrow + 5;
            float2 s = {0.f, 0.f};
            for (int ll = lmin; ll < 6; ++ll) {
                float w = WI2[k2 * 726 + ll * 121 + mfull * 11 + n];
                float2 z = z2s[ll * 66 + mrow * 11 + n];
                s.x += w * z.x; s.y += w * z.y;
            }
            fh2[i] = s;
        }
        __syncthreads();
        for (int i = tid; i < 864; i += 256) {
            int k2 = i / 72, rr = i - k2 * 72, mrow = rr / 12, g = rr - mrow * 12;
            float2 s = {0.f, 0.f};
            #pragma unroll
            for (int n = 0; n < 11; ++n) {
                float2 f = fh2[k2 * 66 + mrow * 11 + n], e = EA2[n * 12 + g];
                s.x += f.x * e.x - f.y * e.y;
                s.y += f.x * e.y + f.y * e.x;
            }
            t2[i] = s;
        }
        __syncthreads();
        float partial = 0.f;
        for (int i = tid; i < 864; i += 256) {
            int k2 = i / 72, rr = i - k2 * 72, a = rr / 12, g = rr - a * 12;
            float base = t2[k2 * 72 + g].x;
            float se = 0.f, so = 0.f;
            #pragma unroll
            for (int d = 1; d < 6; ++d) {
                float2 e = EA2[(5 + d) * 12 + a];
                float2 t = t2[k2 * 72 + d * 12 + g];
                float c = 2.f * (e.x * t.x - e.y * t.y);
                if (d & 1) so += c; else se += c;
            }
            float y0 = base + se + so, y1 = base + se - so;
            float w = WIT[k2];
            if (y0 > 0.f) partial += w * y0;
            if (y1 > 0.f) partial += w * y1;
        }
        for (int off = 32; off > 0; off >>= 1) partial += __shfl_down(partial, off, 64);
        if ((tid & 63) == 0) red[tid >> 6] = partial;
        __syncthreads();
        if (tid == 0) featg[b * 40 + o0 + oL] =
            (red[0] + red[1] + red[2] + red[3]) * (1.0f / 144.0f);
        __syncthreads();
    }
}

// ---------------------------------------------------------------------------
__global__ __launch_bounds__(256) void final_kernel(const float* __restrict__ ws,
                                                    const float* __restrict__ wl,
                                                    const float* __restrict__ bl,
                                                    float* __restrict__ out) {
    int idx = blockIdx.x * 256 + threadIdx.x;
    if (idx >= 1280) return;
    int b = idx / 10, f = idx % 10;
    const float* feat = ws + OFF_FEAT;
    float s = bl[f];
    for (int o = 0; o < 40; ++o) s += feat[b * 40 + o] * wl[f * 40 + o];
    out[idx] = s;
}

// ---------------------------------------------------------------------------
extern "C" void kernel_launch(void* const* d_in, const int* in_sizes, int n_in,
                              void* d_out, int out_size, void* d_ws, size_t ws_size,
                              hipStream_t stream) {
    (void)in_sizes; (void)n_in; (void)out_size; (void)ws_size;
    const float* x  = (const float*)d_in[0];
    const float* k1 = (const float*)d_in[1];
    const float* k2 = (const float*)d_in[2];
    const float* wl = (const float*)d_in[3];
    const float* bl = (const float*)d_in[4];
    float* out = (float*)d_out;
    float* ws  = (float*)d_ws;

    build_tables_kernel<<<829, 256, 0, stream>>>(ws);
    prep_kernel<<<600, 256, 0, stream>>>(ws, k1, k2, x);
    stage1_kernel<<<128 * 20, 256, 0, stream>>>(
        ws + OFF_WINV1, ws + OFF_WSO3, ws + OFF_EA1, ws + OFF_FF2,
        (const float2*)(ws + OFF_X), (const float2*)(ws + OFF_PSI),
        (const int*)(ws + OFF_VTAB), (float2*)(ws + OFF_X2P));
    stage2_kernel<<<128 * 10, 256, 0, stream>>>(ws);
    final_kernel<<<5, 256, 0, stream>>>(ws, wl, bl, out);
}